// Round 14
// baseline (128.615 us; speedup 1.0000x reference)
//
#include <hip/hip_runtime.h>
#include <cstdint>
#include <cstddef>

// B=16 S=1024 D=256 H=8 HD=32 F=1024
#define SDn (1024*256)   // 262144

typedef unsigned short u16;
typedef unsigned int   u32;
typedef __bf16 bf16x8 __attribute__((ext_vector_type(8)));
typedef u16    u16x4v __attribute__((ext_vector_type(4)));
typedef u32    u32x4v __attribute__((ext_vector_type(4)));
typedef float  f32x4  __attribute__((ext_vector_type(4)));
typedef float  f32x16 __attribute__((ext_vector_type(16)));

__device__ __forceinline__ u16 f2bf(float f){
  u32 u = __builtin_bit_cast(u32, f);
  u32 r = u + 0x7FFFu + ((u >> 16) & 1u);
  return (u16)(r >> 16);
}
__device__ __forceinline__ float bf2f(u16 v){
  return __builtin_bit_cast(float, (u32)v << 16);
}

#if __has_builtin(__builtin_amdgcn_exp2f)
#define EXP2(x) __builtin_amdgcn_exp2f(x)
#else
#define EXP2(x) exp2f(x)
#endif

// pack two f32 -> one u32 holding {lo: bf16(a), hi: bf16(b)}
__device__ __forceinline__ u32 cvtpk(float a, float b){
  u32 r;
  asm("v_cvt_pk_bf16_f32 %0, %1, %2" : "=v"(r) : "v"(a), "v"(b));
  return r;
}

// async global->LDS, 16B per lane. LDS dest must be wave-uniform base + lane*16.
__device__ __forceinline__ void gll16(const void* g, void* l){
  __builtin_amdgcn_global_load_lds((const __attribute__((address_space(1))) void*)g,
                                   (__attribute__((address_space(3))) void*)l, 16, 0, 0);
}

// ---------------- prep: weight cast + LN1 partials + x->bf16 (one launch) ----
__global__ void prep(const float* __restrict__ x, float2* __restrict__ part,
                     u16* __restrict__ xb,
                     const float* __restrict__ cw0, const float* __restrict__ cw1,
                     const float* __restrict__ cw2, const float* __restrict__ cw3,
                     u16* __restrict__ co0, u16* __restrict__ co1,
                     u16* __restrict__ co2, u16* __restrict__ co3)
{
  const int bid = blockIdx.x, t = threadIdx.x;
  if (bid < 768){
    int i = bid*256 + t;   // vec4 index over 196608
    const float* src; u16* dst; int j = i;
    if      (j <  49152){ src = cw0; dst = co0; }
    else if (j <  65536){ src = cw1; dst = co1; j -=  49152; }
    else if (j < 131072){ src = cw2; dst = co2; j -=  65536; }
    else               { src = cw3; dst = co3; j -= 131072; }
    float4 v = ((const float4*)src)[j];
    u16x4v o; o[0]=f2bf(v.x); o[1]=f2bf(v.y); o[2]=f2bf(v.z); o[3]=f2bf(v.w);
    ((u16x4v*)dst)[j] = o;
    return;
  }
  __shared__ float2 red[4];
  const int i = bid - 768;
  const int b = i >> 6, c = i & 63;
  const size_t off = (size_t)b*SDn + (size_t)c*4096;
  const float4* p = (const float4*)(x + off);
  u16x4v* pxb = (u16x4v*)(xb + off);
  float s = 0.f, q = 0.f;
  #pragma unroll
  for (int k=0;k<4;k++){
    float4 v = p[t + k*256];
    s += v.x+v.y+v.z+v.w;
    q += v.x*v.x + v.y*v.y + v.z*v.z + v.w*v.w;
    u16x4v o; o[0]=f2bf(v.x); o[1]=f2bf(v.y); o[2]=f2bf(v.z); o[3]=f2bf(v.w);
    pxb[t + k*256] = o;
  }
  #pragma unroll
  for (int o=32;o;o>>=1){ s += __shfl_down(s,o); q += __shfl_down(q,o); }
  if ((t & 63) == 0) red[t>>6] = make_float2(s,q);
  __syncthreads();
  if (t == 0){
    float S=0.f,Q=0.f;
    #pragma unroll
    for (int k=0;k<4;k++){ S += red[k].x; Q += red[k].y; }
    part[b*64 + c] = make_float2(S,Q);
  }
}

// ---------------- LN apply (64-partial reduce), input bf16 -------------------
__global__ void ln_apply(const u16* __restrict__ xin, const float* __restrict__ gamma,
                         const float* __restrict__ beta, const float2* __restrict__ part,
                         u16* __restrict__ y)
{ // grid (64 chunks, 16 batches), block 256
  int b = blockIdx.y, c = blockIdx.x, t = threadIdx.x;
  __shared__ float2 stat;
  if (t < 64){
    float2 v = part[b*64 + t];
    float s = v.x, q = v.y;
    #pragma unroll
    for (int o=32;o;o>>=1){ s += __shfl_down(s,o); q += __shfl_down(q,o); }
    if (t == 0){
      float mean = s / (float)SDn;
      float var  = q / (float)SDn - mean*mean;
      stat = make_float2(mean, rsqrtf(var + 1e-5f));
    }
  }
  __syncthreads();
  const float mean = stat.x, rstd = stat.y;
  const size_t off = (size_t)b*SDn + (size_t)c*4096;
  const u16x4v* px = (const u16x4v*)(xin + off);
  const float4* pg = (const float4*)(gamma + (size_t)c*4096);
  const float4* pb = (const float4*)(beta  + (size_t)c*4096);
  u16x4v* py = (u16x4v*)(y + off);
  #pragma unroll
  for (int i=0;i<4;i++){
    u16x4v xv = px[t + i*256];
    float4 gv = pg[t + i*256];
    float4 bv = pb[t + i*256];
    u16x4v o;
    o[0] = f2bf(gv.x*(bf2f(xv[0])-mean)*rstd + bv.x);
    o[1] = f2bf(gv.y*(bf2f(xv[1])-mean)*rstd + bv.y);
    o[2] = f2bf(gv.z*(bf2f(xv[2])-mean)*rstd + bv.z);
    o[3] = f2bf(gv.w*(bf2f(xv[3])-mean)*rstd + bv.w);
    py[t + i*256] = o;
  }
}

// ---------------- 128x128 bf16 MFMA GEMM, C = A @ W^T, 2-phase prefetch ------
// EPI 0: QKV scatter (bias, split q/k/vt, q pre-scaled log2e/sqrt(32))
// EPI 2: o0 = bf16(relu(acc + bias))
template<int EPI>
__launch_bounds__(256, 4)
__global__ void gemm128(const u16* __restrict__ A, const u16* __restrict__ W,
                        const float* __restrict__ bias,
                        u16* __restrict__ o0, u16* __restrict__ o1, u16* __restrict__ o2,
                        int K, int N)
{
  __shared__ u16 As[2][4096];
  __shared__ u16 Bs[2][4096];
  const int tid  = threadIdx.x;
  const int lane = tid & 63;
  const int wid  = tid >> 6;
  const int wm = wid >> 1, wn = wid & 1;
  const int g  = lane >> 4;
  const int lr = lane & 15;
  const int m0 = blockIdx.x * 128;
  const int n0 = blockIdx.y * 128;

  f32x4 zf = {0.f,0.f,0.f,0.f};
  f32x4 acc[4][4];
  #pragma unroll
  for (int i=0;i<4;i++)
    #pragma unroll
    for (int j=0;j<4;j++) acc[i][j] = zf;

  const int r0 = tid >> 2, c0 = tid & 3;
  const int cs = c0 ^ ((r0 >> 1) & 3);
  const u16* Ar0 = A + (size_t)(m0 + r0     )*K + cs*8;
  const u16* Ar1 = A + (size_t)(m0 + r0 + 64)*K + cs*8;
  const u16* Wr0 = W + (size_t)(n0 + r0     )*K + cs*8;
  const u16* Wr1 = W + (size_t)(n0 + r0 + 64)*K + cs*8;

  int aoff[4], boff[4];
  #pragma unroll
  for (int m=0;m<4;m++){
    int ra = wm*64 + m*16 + lr;
    aoff[m] = (ra*4 + (g ^ ((ra>>1)&3))) * 8;
    int rb = wn*64 + m*16 + lr;
    boff[m] = (rb*4 + (g ^ ((rb>>1)&3))) * 8;
  }

  auto STAGE = [&](int buf, int k0){
    gll16(Ar0 + k0, &As[buf][tid*8]);
    gll16(Ar1 + k0, &As[buf][(tid+256)*8]);
    gll16(Wr0 + k0, &Bs[buf][tid*8]);
    gll16(Wr1 + k0, &Bs[buf][(tid+256)*8]);
  };

  STAGE(0, 0);
  __syncthreads();
  int cur = 0;
  for (int k0 = 0; k0 < K; k0 += 32){
    if (k0 + 32 < K) STAGE(cur^1, k0 + 32);
    bf16x8 af[4], bfv[4];
    #pragma unroll
    for (int m=0;m<4;m++) af[m]  = *(const bf16x8*)(&As[cur][aoff[m]]);
    #pragma unroll
    for (int n=0;n<4;n++) bfv[n] = *(const bf16x8*)(&Bs[cur][boff[n]]);
    #pragma unroll
    for (int m=0;m<4;m++)
      #pragma unroll
      for (int n=0;n<4;n++)
        acc[m][n] = __builtin_amdgcn_mfma_f32_16x16x32_bf16(af[m], bfv[n], acc[m][n], 0, 0, 0);
    __syncthreads();
    cur ^= 1;
  }

  #pragma unroll
  for (int m=0;m<4;m++){
    const int rowb = m0 + wm*64 + m*16 + g*4;
    #pragma unroll
    for (int n=0;n<4;n++){
      const int col = n0 + wn*64 + n*16 + lr;
      const float bc = bias[col];
      if constexpr (EPI == 0){
        const int hh  = col / 96;
        const int rem = col - hh*96;
        const int which = rem >> 5;
        const int d = rem & 31;
        const int b = rowb >> 10, s0 = rowb & 1023;   // 4 rr rows share b
        if (which == 2){
          u16x4v pv;
          #pragma unroll
          for (int rr=0;rr<4;rr++) pv[rr] = f2bf(acc[m][n][rr] + bc);
          *(u16x4v*)(o2 + ((size_t)((b*8 + hh)*32 + d))*1024 + s0) = pv;
        } else {
          #pragma unroll
          for (int rr=0;rr<4;rr++){
            float v = acc[m][n][rr] + bc;
            if (which == 0)   // q, scaled by log2(e)/sqrt(HD) so attn uses raw exp2
              o0[((size_t)((b*8 + hh)*1024 + s0 + rr))*32 + d] = f2bf(v * (0.17677669529663689f * 1.4426950408889634f));
            else
              o1[((size_t)((b*8 + hh)*1024 + s0 + rr))*32 + d] = f2bf(v);
          }
        }
      } else {
        #pragma unroll
        for (int rr=0;rr<4;rr++){
          float v = acc[m][n][rr] + bc;
          o0[(size_t)(rowb + rr) * N + col] = f2bf(v > 0.f ? v : 0.f);
        }
      }
    }
  }
}

// ---------------- 64x128 bf16 MFMA GEMM: out = bf16res + A@W^T + bias (fp32) -
__launch_bounds__(256, 4)
__global__ void gemm64(const u16* __restrict__ A, const u16* __restrict__ W,
                       const float* __restrict__ bias, const u16* __restrict__ res,
                       float* __restrict__ outF, int K, int N)
{
  __shared__ u16 As[2][2048];
  __shared__ u16 Bs[2][4096];
  const int tid  = threadIdx.x;
  const int lane = tid & 63;
  const int wid  = tid >> 6;
  const int g  = lane >> 4;
  const int lr = lane & 15;
  const int m0 = blockIdx.x * 64;
  const int n0 = blockIdx.y * 128;

  f32x4 zf = {0.f,0.f,0.f,0.f};
  f32x4 acc[4][2];
  #pragma unroll
  for (int i=0;i<4;i++){ acc[i][0]=zf; acc[i][1]=zf; }

  const int r0 = tid >> 2, c0 = tid & 3;
  const int cs = c0 ^ ((r0 >> 1) & 3);
  const u16* Asrc  = A + (size_t)(m0 + r0)*K + cs*8;
  const u16* Wsrc0 = W + (size_t)(n0 + r0     )*K + cs*8;
  const u16* Wsrc1 = W + (size_t)(n0 + r0 + 64)*K + cs*8;

  int aoff[4], boff[2];
  #pragma unroll
  for (int m=0;m<4;m++){
    int ra = m*16 + lr;
    aoff[m] = (ra*4 + (g ^ ((ra>>1)&3))) * 8;
  }
  #pragma unroll
  for (int n=0;n<2;n++){
    int rb = wid*32 + n*16 + lr;
    boff[n] = (rb*4 + (g ^ ((rb>>1)&3))) * 8;
  }

  auto STAGE = [&](int buf, int k0){
    gll16(Asrc  + k0, &As[buf][tid*8]);
    gll16(Wsrc0 + k0, &Bs[buf][tid*8]);
    gll16(Wsrc1 + k0, &Bs[buf][(tid+256)*8]);
  };

  STAGE(0, 0);
  __syncthreads();
  int cur = 0;
  for (int k0 = 0; k0 < K; k0 += 32){
    if (k0 + 32 < K) STAGE(cur^1, k0 + 32);
    bf16x8 af[4], bfv[2];
    #pragma unroll
    for (int m=0;m<4;m++) af[m]  = *(const bf16x8*)(&As[cur][aoff[m]]);
    #pragma unroll
    for (int n=0;n<2;n++) bfv[n] = *(const bf16x8*)(&Bs[cur][boff[n]]);
    #pragma unroll
    for (int m=0;m<4;m++)
      #pragma unroll
      for (int n=0;n<2;n++)
        acc[m][n] = __builtin_amdgcn_mfma_f32_16x16x32_bf16(af[m], bfv[n], acc[m][n], 0, 0, 0);
    __syncthreads();
    cur ^= 1;
  }

  #pragma unroll
  for (int m=0;m<4;m++){
    const int rowb = m0 + m*16 + g*4;
    #pragma unroll
    for (int n=0;n<2;n++){
      const int col = n0 + wid*32 + n*16 + lr;
      const float bc = bias[col];
      #pragma unroll
      for (int rr=0;rr<4;rr++){
        size_t idx = (size_t)(rowb + rr) * N + col;
        outF[idx] = bf2f(res[idx]) + acc[m][n][rr] + bc;
      }
    }
  }
}

// ---------------- fused attention + O-projection -----------------------------
// Main loop v4: BARRIER-FREE register-prefetched flash attn. K/V fragments are
// read per-lane from global (XCD-L2-hot, R12-verified indices) into a DOUBLE-
// BUFFERED register set one full tile ahead (T14 issue-early/use-late): tile
// t+1's 16 independent 16B loads issue before tile t's ~600cy of compute, so
// L2 latency is hidden without LDS or __syncthreads (R12's failure was the
// missing prefetch). ~128 VGPR of prefetch state -> launch_bounds(256,2).
// Epilogue (R11, measured-best): O -> LDS T, mini-GEMM with Wo LDS-staged.
__launch_bounds__(256, 2)
__global__ void attn32f(const u16* __restrict__ Q, const u16* __restrict__ Kb,
                        const u16* __restrict__ Vt, const u16* __restrict__ Wob,
                        const float* __restrict__ bo, const u16* __restrict__ xb,
                        u16* __restrict__ x1b, float2* __restrict__ part2)
{
  __shared__ u16 smem[20480];   // 40KB: Wo dbuf [0,32KB) + T [32KB,40KB)
  const int tid  = threadIdx.x;
  const int lane = tid & 63;
  const int wid  = tid >> 6;
  const int l31  = lane & 31;
  const int l5   = lane >> 5;
  const int lr   = lane & 15;
  const int g    = lane >> 4;
  const int bh = blockIdx.x;
  const int qx = blockIdx.y;
  const int q0 = qx * 128;
  const size_t base = (size_t)bh * (1024*32);

  const int qrow = q0 + wid*32 + l31;
  const bf16x8 qf0 = *(const bf16x8*)(Q + base + (size_t)qrow*32 + l5*8);
  const bf16x8 qf1 = *(const bf16x8*)(Q + base + (size_t)qrow*32 + 16 + l5*8);

  f32x16 acc = {};     // O[q=(r&3)+8(r>>2)+4*l5][d=l31]
  float lsum = 0.f;

  const u16* Kb0 = Kb + base;                       // [1024 kv][32 d]
  const u16* Vr  = Vt + base + (size_t)l31*1024;    // V^T row d=l31

  bf16x8 kA[8], vA[8], kB[8], vB[8];

  auto LOADT = [&](bf16x8 (&KS)[8], bf16x8 (&VS)[8], int kv0){
    #pragma unroll
    for (int G=0; G<4; ++G){
      const u16* kr = Kb0 + (size_t)(kv0 + 32*G + l31)*32;
      KS[2*G+0] = *(const bf16x8*)(kr + l5*8);
      KS[2*G+1] = *(const bf16x8*)(kr + 16 + l5*8);
      VS[2*G+0] = *(const bf16x8*)(Vr + kv0 + (4*G     + l5)*8);
      VS[2*G+1] = *(const bf16x8*)(Vr + kv0 + (4*G + 2 + l5)*8);
    }
  };

  auto COMPUTE = [&](bf16x8 (&KS)[8], bf16x8 (&VS)[8]){
    #pragma unroll
    for (int G=0; G<4; ++G){
      f32x16 sf = __builtin_amdgcn_mfma_f32_32x32x16_bf16(KS[2*G+0], qf0, (f32x16){}, 0, 0, 0);
      sf = __builtin_amdgcn_mfma_f32_32x32x16_bf16(KS[2*G+1], qf1, sf, 0, 0, 0);

      u32 W[8];
      #pragma unroll
      for (int j=0;j<4;j++){
        float p0 = EXP2(sf[4*j+0]);
        float p1 = EXP2(sf[4*j+1]);
        float p2 = EXP2(sf[4*j+2]);
        float p3 = EXP2(sf[4*j+3]);
        lsum += (p0 + p1) + (p2 + p3);
        W[2*j+0] = cvtpk(p0, p1);
        W[2*j+1] = cvtpk(p2, p3);
      }

      #pragma unroll
      for (int sl=0; sl<2; ++sl){
        u32 a0 = W[4*sl + 0], b0 = W[4*sl + 2];
        u32 a1 = W[4*sl + 1], b1 = W[4*sl + 3];
        asm("v_permlane32_swap_b32 %0, %1" : "+v"(a0), "+v"(b0));
        asm("v_permlane32_swap_b32 %0, %1" : "+v"(a1), "+v"(b1));
        bf16x8 pa = __builtin_bit_cast(bf16x8, (u32x4v){a0, a1, b0, b1});
        acc = __builtin_amdgcn_mfma_f32_32x32x16_bf16(pa, VS[2*G+sl], acc, 0, 0, 0);
      }
    }
  };

  LOADT(kA, vA, 0);
  #pragma unroll
  for (int t = 0; t < 8; t += 2){
    if (t + 1 < 8) LOADT(kB, vB, (t+1)*128);
    COMPUTE(kA, vA);
    if (t + 2 < 8) LOADT(kA, vA, (t+2)*128);
    COMPUTE(kB, vB);
  }

  // ---- epilogue part 1: normalize O, write T[16][256] (slot = chunk ^ row) --
  lsum += __shfl_xor(lsum, 32);
  float inv = 1.0f / lsum;
  u16* T = smem + 16384;
  #pragma unroll
  for (int r=0;r<16;r++){
    int qloc = (r&3) + 8*(r>>2) + 4*l5;
    float iv = __shfl(inv, qloc);
    int row = wid*4 + (r>>2);                 // 0..15
    int col = ((r&3) + 4*l5)*32 + l31;        // 0..255
    int ch  = col >> 3;
    T[row*256 + ((ch ^ row) << 3) + (col & 7)] = f2bf(acc[r] * iv);
  }

  // ---- epilogue part 2: mini-GEMM x1[16][256] = T @ Wo^T (Wo LDS dbuf) ------
  auto stageWo = [&](int buf, int k0){
    u16* dst = smem + buf*8192;
    #pragma unroll
    for (int j=0;j<4;j++){
      int ch = tid + j*256;
      int n = ch >> 2, c = ch & 3;
      int kcc = c ^ ((n>>1)&3);
      gll16(Wob + (size_t)n*256 + k0 + kcc*8, dst + ch*8);
    }
  };
  stageWo(0, 0);
  __syncthreads();   // covers T writes + WoS[0]

  f32x4 zf4 = {0.f,0.f,0.f,0.f};
  f32x4 acc2[4] = {zf4, zf4, zf4, zf4};
  int cw = 0;
  #pragma unroll
  for (int kk=0; kk<8; ++kk){
    if (kk < 7) stageWo(cw^1, (kk+1)*32);
    bf16x8 af = *(const bf16x8*)(T + lr*256 + (((4*kk + g) ^ lr) << 3));
    #pragma unroll
    for (int nt=0; nt<4; ++nt){
      int n = wid*64 + nt*16 + lr;
      bf16x8 bw = *(const bf16x8*)(smem + cw*8192 + n*32 + ((g ^ ((n>>1)&3)) << 3));
      acc2[nt] = __builtin_amdgcn_mfma_f32_16x16x32_bf16(af, bw, acc2[nt], 0, 0, 0);
    }
    __syncthreads();
    cw ^= 1;
  }

  // ---- epilogue part 3: bias + residual(xb) -> x1b + LN2 stats ---------------
  const int b = bh >> 3, h = bh & 7;
  const int srow0 = h*128 + qx*16;
  float ss = 0.f, qq = 0.f;
  #pragma unroll
  for (int nt=0; nt<4; ++nt){
    int col = wid*64 + nt*16 + lr;
    float bc = bo[col];
    #pragma unroll
    for (int rr=0; rr<4; ++rr){
      int row = g*4 + rr;
      size_t idx = ((size_t)b*1024 + srow0 + row)*256 + col;
      float v = bf2f(xb[idx]) + acc2[nt][rr] + bc;
      x1b[idx] = f2bf(v);
      ss += v; qq += v*v;
    }
  }
  #pragma unroll
  for (int o=32;o;o>>=1){ ss += __shfl_down(ss,o); qq += __shfl_down(qq,o); }
  float2* sred = (float2*)smem;   // staging region dead after final barrier
  if (lane == 0) sred[wid] = make_float2(ss, qq);
  __syncthreads();
  if (tid == 0){
    float S=0.f, QQ=0.f;
    #pragma unroll
    for (int k2=0;k2<4;k2++){ S += sred[k2].x; QQ += sred[k2].y; }
    part2[b*64 + h*8 + qx] = make_float2(S, QQ);
  }
}

// ---------------- launcher ---------------------------------------------------
extern "C" void kernel_launch(void* const* d_in, const int* in_sizes, int n_in,
                              void* d_out, int out_size, void* d_ws, size_t ws_size,
                              hipStream_t stream)
{
  const float* x      = (const float*)d_in[0];
  const float* gamma1 = (const float*)d_in[1];
  const float* beta1  = (const float*)d_in[2];
  const float* Wqkv   = (const float*)d_in[3];
  const float* bqkv   = (const float*)d_in[4];
  const float* Wo     = (const float*)d_in[5];
  const float* bo     = (const float*)d_in[6];
  const float* gamma2 = (const float*)d_in[7];
  const float* beta2  = (const float*)d_in[8];
  const float* W1     = (const float*)d_in[9];
  const float* b1     = (const float*)d_in[10];
  const float* W2     = (const float*)d_in[11];
  const float* b2     = (const float*)d_in[12];
  float* out = (float*)d_out;
  char* ws = (char*)d_ws;

  float2* part  = (float2*)(ws + 256);        //  8 KB  (LN1 partials, 16x64)
  float2* part2 = (float2*)(ws + 8448);       //  8 KB  (LN2 partials, 16x64)
  u16* wq   = (u16*)(ws + 16896);             // 384 KB (768x256)
  u16* wo   = (u16*)(ws + 410112);            // 128 KB (256x256)
  u16* w1   = (u16*)(ws + 541184);            // 512 KB (1024x256)
  u16* w2   = (u16*)(ws + 1065472);           // 512 KB (256x1024)
  u16* hbuf = (u16*)(ws + 1589760);           //  8 MB  LN output bf16
  u16* qb   = (u16*)(ws + 9978368);           //  8 MB  [B,H,S,32]
  u16* kb   = (u16*)(ws + 18366976);          //  8 MB  [B,H,S,32]
  u16* vtb  = (u16*)(ws + 26755584);          //  8 MB  [B,H,32,S]
  u16* xb   = (u16*)(ws + 35144192);          //  8 MB  x as bf16
  u16* midb = (u16*)(ws + 9978368);           // 32 MB  (reuses qb..xb region after attn)
  u16* x1b  = (u16*)(ws + 43532800);          //  8 MB  x1 residual, bf16

  // prep: weight cast + LN1 partials + x->bf16 (one launch, disjoint blocks)
  prep<<<1792, 256, 0, stream>>>(x, part, xb, Wqkv, Wo, W1, W2, wq, wo, w1, w2);

  // LN1 apply -> hbuf (bf16)
  ln_apply<<<dim3(64,16), 256, 0, stream>>>(xb, gamma1, beta1, part, hbuf);

  // QKV projection -> q (scaled), k, v^T
  gemm128<0><<<dim3(128,6), 256, 0, stream>>>(hbuf, wq, bqkv, qb, kb, vtb, 256, 768);

  // attention + O-proj + residual(xb) -> x1b (bf16) + LN2 partial stats
  attn32f<<<dim3(128,8), 256, 0, stream>>>(qb, kb, vtb, wo, bo, xb, x1b, part2);

  // LN2 apply (64 partials) -> hbuf (bf16)
  ln_apply<<<dim3(64,16), 256, 0, stream>>>(x1b, gamma2, beta2, part2, hbuf);

  // MLP1 + bias + ReLU -> midb (bf16)
  gemm128<2><<<dim3(128,8), 256, 0, stream>>>(hbuf, w1, b1, midb, nullptr, nullptr, 256, 1024);

  // MLP2 + bias + residual(x1b) -> out (fp32, final)
  gemm64<<<dim3(256,2), 256, 0, stream>>>(midb, w2, b2, x1b, out, 1024, 256);
}

// Round 15
// 106.815 us; speedup vs baseline: 1.2041x; 1.2041x over previous
//
#include <hip/hip_runtime.h>
#include <cstdint>
#include <cstddef>

// B=16 S=1024 D=256 H=8 HD=32 F=1024
#define SDn (1024*256)   // 262144

typedef unsigned short u16;
typedef unsigned int   u32;
typedef __bf16 bf16x8 __attribute__((ext_vector_type(8)));
typedef u16    u16x4v __attribute__((ext_vector_type(4)));
typedef u32    u32x4v __attribute__((ext_vector_type(4)));
typedef float  f32x4  __attribute__((ext_vector_type(4)));
typedef float  f32x16 __attribute__((ext_vector_type(16)));

__device__ __forceinline__ u16 f2bf(float f){
  u32 u = __builtin_bit_cast(u32, f);
  u32 r = u + 0x7FFFu + ((u >> 16) & 1u);
  return (u16)(r >> 16);
}
__device__ __forceinline__ float bf2f(u16 v){
  return __builtin_bit_cast(float, (u32)v << 16);
}

#if __has_builtin(__builtin_amdgcn_exp2f)
#define EXP2(x) __builtin_amdgcn_exp2f(x)
#else
#define EXP2(x) exp2f(x)
#endif

// pack two f32 -> one u32 holding {lo: bf16(a), hi: bf16(b)}
__device__ __forceinline__ u32 cvtpk(float a, float b){
  u32 r;
  asm("v_cvt_pk_bf16_f32 %0, %1, %2" : "=v"(r) : "v"(a), "v"(b));
  return r;
}

// async global->LDS, 16B per lane. LDS dest must be wave-uniform base + lane*16.
__device__ __forceinline__ void gll16(const void* g, void* l){
  __builtin_amdgcn_global_load_lds((const __attribute__((address_space(1))) void*)g,
                                   (__attribute__((address_space(3))) void*)l, 16, 0, 0);
}

// ---------------- prep: weight cast + LN1 partials + x->bf16 (one launch) ----
__global__ void prep(const float* __restrict__ x, float2* __restrict__ part,
                     u16* __restrict__ xb,
                     const float* __restrict__ cw0, const float* __restrict__ cw1,
                     const float* __restrict__ cw2, const float* __restrict__ cw3,
                     u16* __restrict__ co0, u16* __restrict__ co1,
                     u16* __restrict__ co2, u16* __restrict__ co3)
{
  const int bid = blockIdx.x, t = threadIdx.x;
  if (bid < 768){
    int i = bid*256 + t;   // vec4 index over 196608
    const float* src; u16* dst; int j = i;
    if      (j <  49152){ src = cw0; dst = co0; }
    else if (j <  65536){ src = cw1; dst = co1; j -=  49152; }
    else if (j < 131072){ src = cw2; dst = co2; j -=  65536; }
    else               { src = cw3; dst = co3; j -= 131072; }
    float4 v = ((const float4*)src)[j];
    u16x4v o; o[0]=f2bf(v.x); o[1]=f2bf(v.y); o[2]=f2bf(v.z); o[3]=f2bf(v.w);
    ((u16x4v*)dst)[j] = o;
    return;
  }
  __shared__ float2 red[4];
  const int i = bid - 768;
  const int b = i >> 6, c = i & 63;
  const size_t off = (size_t)b*SDn + (size_t)c*4096;
  const float4* p = (const float4*)(x + off);
  u16x4v* pxb = (u16x4v*)(xb + off);
  float s = 0.f, q = 0.f;
  #pragma unroll
  for (int k=0;k<4;k++){
    float4 v = p[t + k*256];
    s += v.x+v.y+v.z+v.w;
    q += v.x*v.x + v.y*v.y + v.z*v.z + v.w*v.w;
    u16x4v o; o[0]=f2bf(v.x); o[1]=f2bf(v.y); o[2]=f2bf(v.z); o[3]=f2bf(v.w);
    pxb[t + k*256] = o;
  }
  #pragma unroll
  for (int o=32;o;o>>=1){ s += __shfl_down(s,o); q += __shfl_down(q,o); }
  if ((t & 63) == 0) red[t>>6] = make_float2(s,q);
  __syncthreads();
  if (t == 0){
    float S=0.f,Q=0.f;
    #pragma unroll
    for (int k=0;k<4;k++){ S += red[k].x; Q += red[k].y; }
    part[b*64 + c] = make_float2(S,Q);
  }
}

// ---------------- LN apply (64-partial reduce), input bf16 -------------------
__global__ void ln_apply(const u16* __restrict__ xin, const float* __restrict__ gamma,
                         const float* __restrict__ beta, const float2* __restrict__ part,
                         u16* __restrict__ y)
{ // grid (64 chunks, 16 batches), block 256
  int b = blockIdx.y, c = blockIdx.x, t = threadIdx.x;
  __shared__ float2 stat;
  if (t < 64){
    float2 v = part[b*64 + t];
    float s = v.x, q = v.y;
    #pragma unroll
    for (int o=32;o;o>>=1){ s += __shfl_down(s,o); q += __shfl_down(q,o); }
    if (t == 0){
      float mean = s / (float)SDn;
      float var  = q / (float)SDn - mean*mean;
      stat = make_float2(mean, rsqrtf(var + 1e-5f));
    }
  }
  __syncthreads();
  const float mean = stat.x, rstd = stat.y;
  const size_t off = (size_t)b*SDn + (size_t)c*4096;
  const u16x4v* px = (const u16x4v*)(xin + off);
  const float4* pg = (const float4*)(gamma + (size_t)c*4096);
  const float4* pb = (const float4*)(beta  + (size_t)c*4096);
  u16x4v* py = (u16x4v*)(y + off);
  #pragma unroll
  for (int i=0;i<4;i++){
    u16x4v xv = px[t + i*256];
    float4 gv = pg[t + i*256];
    float4 bv = pb[t + i*256];
    u16x4v o;
    o[0] = f2bf(gv.x*(bf2f(xv[0])-mean)*rstd + bv.x);
    o[1] = f2bf(gv.y*(bf2f(xv[1])-mean)*rstd + bv.y);
    o[2] = f2bf(gv.z*(bf2f(xv[2])-mean)*rstd + bv.z);
    o[3] = f2bf(gv.w*(bf2f(xv[3])-mean)*rstd + bv.w);
    py[t + i*256] = o;
  }
}

// ---------------- 128x128 bf16 MFMA GEMM, C = A @ W^T, 2-phase prefetch ------
// EPI 0: QKV scatter (bias, split q/k/vt, q pre-scaled log2e/sqrt(32))
// EPI 2: o0 = bf16(relu(acc + bias))
template<int EPI>
__launch_bounds__(256, 4)
__global__ void gemm128(const u16* __restrict__ A, const u16* __restrict__ W,
                        const float* __restrict__ bias,
                        u16* __restrict__ o0, u16* __restrict__ o1, u16* __restrict__ o2,
                        int K, int N)
{
  __shared__ u16 As[2][4096];
  __shared__ u16 Bs[2][4096];
  const int tid  = threadIdx.x;
  const int lane = tid & 63;
  const int wid  = tid >> 6;
  const int wm = wid >> 1, wn = wid & 1;
  const int g  = lane >> 4;
  const int lr = lane & 15;
  const int m0 = blockIdx.x * 128;
  const int n0 = blockIdx.y * 128;

  f32x4 zf = {0.f,0.f,0.f,0.f};
  f32x4 acc[4][4];
  #pragma unroll
  for (int i=0;i<4;i++)
    #pragma unroll
    for (int j=0;j<4;j++) acc[i][j] = zf;

  const int r0 = tid >> 2, c0 = tid & 3;
  const int cs = c0 ^ ((r0 >> 1) & 3);
  const u16* Ar0 = A + (size_t)(m0 + r0     )*K + cs*8;
  const u16* Ar1 = A + (size_t)(m0 + r0 + 64)*K + cs*8;
  const u16* Wr0 = W + (size_t)(n0 + r0     )*K + cs*8;
  const u16* Wr1 = W + (size_t)(n0 + r0 + 64)*K + cs*8;

  int aoff[4], boff[4];
  #pragma unroll
  for (int m=0;m<4;m++){
    int ra = wm*64 + m*16 + lr;
    aoff[m] = (ra*4 + (g ^ ((ra>>1)&3))) * 8;
    int rb = wn*64 + m*16 + lr;
    boff[m] = (rb*4 + (g ^ ((rb>>1)&3))) * 8;
  }

  auto STAGE = [&](int buf, int k0){
    gll16(Ar0 + k0, &As[buf][tid*8]);
    gll16(Ar1 + k0, &As[buf][(tid+256)*8]);
    gll16(Wr0 + k0, &Bs[buf][tid*8]);
    gll16(Wr1 + k0, &Bs[buf][(tid+256)*8]);
  };

  STAGE(0, 0);
  __syncthreads();
  int cur = 0;
  for (int k0 = 0; k0 < K; k0 += 32){
    if (k0 + 32 < K) STAGE(cur^1, k0 + 32);
    bf16x8 af[4], bfv[4];
    #pragma unroll
    for (int m=0;m<4;m++) af[m]  = *(const bf16x8*)(&As[cur][aoff[m]]);
    #pragma unroll
    for (int n=0;n<4;n++) bfv[n] = *(const bf16x8*)(&Bs[cur][boff[n]]);
    #pragma unroll
    for (int m=0;m<4;m++)
      #pragma unroll
      for (int n=0;n<4;n++)
        acc[m][n] = __builtin_amdgcn_mfma_f32_16x16x32_bf16(af[m], bfv[n], acc[m][n], 0, 0, 0);
    __syncthreads();
    cur ^= 1;
  }

  #pragma unroll
  for (int m=0;m<4;m++){
    const int rowb = m0 + wm*64 + m*16 + g*4;
    #pragma unroll
    for (int n=0;n<4;n++){
      const int col = n0 + wn*64 + n*16 + lr;
      const float bc = bias[col];
      if constexpr (EPI == 0){
        const int hh  = col / 96;
        const int rem = col - hh*96;
        const int which = rem >> 5;
        const int d = rem & 31;
        const int b = rowb >> 10, s0 = rowb & 1023;   // 4 rr rows share b
        if (which == 2){
          u16x4v pv;
          #pragma unroll
          for (int rr=0;rr<4;rr++) pv[rr] = f2bf(acc[m][n][rr] + bc);
          *(u16x4v*)(o2 + ((size_t)((b*8 + hh)*32 + d))*1024 + s0) = pv;
        } else {
          #pragma unroll
          for (int rr=0;rr<4;rr++){
            float v = acc[m][n][rr] + bc;
            if (which == 0)   // q, scaled by log2(e)/sqrt(HD) so attn uses raw exp2
              o0[((size_t)((b*8 + hh)*1024 + s0 + rr))*32 + d] = f2bf(v * (0.17677669529663689f * 1.4426950408889634f));
            else
              o1[((size_t)((b*8 + hh)*1024 + s0 + rr))*32 + d] = f2bf(v);
          }
        }
      } else {
        #pragma unroll
        for (int rr=0;rr<4;rr++){
          float v = acc[m][n][rr] + bc;
          o0[(size_t)(rowb + rr) * N + col] = f2bf(v > 0.f ? v : 0.f);
        }
      }
    }
  }
}

// ---------------- 64x128 bf16 MFMA GEMM: out = bf16res + A@W^T + bias (fp32) -
__launch_bounds__(256, 4)
__global__ void gemm64(const u16* __restrict__ A, const u16* __restrict__ W,
                       const float* __restrict__ bias, const u16* __restrict__ res,
                       float* __restrict__ outF, int K, int N)
{
  __shared__ u16 As[2][2048];
  __shared__ u16 Bs[2][4096];
  const int tid  = threadIdx.x;
  const int lane = tid & 63;
  const int wid  = tid >> 6;
  const int g  = lane >> 4;
  const int lr = lane & 15;
  const int m0 = blockIdx.x * 64;
  const int n0 = blockIdx.y * 128;

  f32x4 zf = {0.f,0.f,0.f,0.f};
  f32x4 acc[4][2];
  #pragma unroll
  for (int i=0;i<4;i++){ acc[i][0]=zf; acc[i][1]=zf; }

  const int r0 = tid >> 2, c0 = tid & 3;
  const int cs = c0 ^ ((r0 >> 1) & 3);
  const u16* Asrc  = A + (size_t)(m0 + r0)*K + cs*8;
  const u16* Wsrc0 = W + (size_t)(n0 + r0     )*K + cs*8;
  const u16* Wsrc1 = W + (size_t)(n0 + r0 + 64)*K + cs*8;

  int aoff[4], boff[2];
  #pragma unroll
  for (int m=0;m<4;m++){
    int ra = m*16 + lr;
    aoff[m] = (ra*4 + (g ^ ((ra>>1)&3))) * 8;
  }
  #pragma unroll
  for (int n=0;n<2;n++){
    int rb = wid*32 + n*16 + lr;
    boff[n] = (rb*4 + (g ^ ((rb>>1)&3))) * 8;
  }

  auto STAGE = [&](int buf, int k0){
    gll16(Asrc  + k0, &As[buf][tid*8]);
    gll16(Wsrc0 + k0, &Bs[buf][tid*8]);
    gll16(Wsrc1 + k0, &Bs[buf][(tid+256)*8]);
  };

  STAGE(0, 0);
  __syncthreads();
  int cur = 0;
  for (int k0 = 0; k0 < K; k0 += 32){
    if (k0 + 32 < K) STAGE(cur^1, k0 + 32);
    bf16x8 af[4], bfv[2];
    #pragma unroll
    for (int m=0;m<4;m++) af[m]  = *(const bf16x8*)(&As[cur][aoff[m]]);
    #pragma unroll
    for (int n=0;n<2;n++) bfv[n] = *(const bf16x8*)(&Bs[cur][boff[n]]);
    #pragma unroll
    for (int m=0;m<4;m++)
      #pragma unroll
      for (int n=0;n<2;n++)
        acc[m][n] = __builtin_amdgcn_mfma_f32_16x16x32_bf16(af[m], bfv[n], acc[m][n], 0, 0, 0);
    __syncthreads();
    cur ^= 1;
  }

  #pragma unroll
  for (int m=0;m<4;m++){
    const int rowb = m0 + m*16 + g*4;
    #pragma unroll
    for (int n=0;n<2;n++){
      const int col = n0 + wid*32 + n*16 + lr;
      const float bc = bias[col];
      #pragma unroll
      for (int rr=0;rr<4;rr++){
        size_t idx = (size_t)(rowb + rr) * N + col;
        outF[idx] = bf2f(res[idx]) + acc[m][n][rr] + bc;
      }
    }
  }
}

// ---------------- fused attention + O-projection -----------------------------
// Main loop: R11 structure (K/V global_load_lds dbuf, 32x32 MFMA, in-register
// P via cvt_pk+permlane32_swap). CHANGE vs R11: K stored chunk-column-major
// in LDS (16B chunk L = c*128 + kv) so the K-fragment ds_read_b128 is 4-way
// bank-aliased (the b128 floor) instead of 8-way. Bijection realized via the
// pre-permuted global source (linear gll16 dest, rule 21).
// Epilogue (R11, measured-best): O -> LDS T, mini-GEMM with Wo LDS-staged.
__launch_bounds__(256, 4)
__global__ void attn32f(const u16* __restrict__ Q, const u16* __restrict__ Kb,
                        const u16* __restrict__ Vt, const u16* __restrict__ Wob,
                        const float* __restrict__ bo, const u16* __restrict__ xb,
                        u16* __restrict__ x1b, float2* __restrict__ part2)
{
  __shared__ u16 smem[20480];   // 40KB: K/V dbuf [0,32KB) + T [32KB,40KB)
  const int tid  = threadIdx.x;
  const int lane = tid & 63;
  const int wid  = tid >> 6;
  const int l31  = lane & 31;
  const int l5   = lane >> 5;
  const int lr   = lane & 15;
  const int g    = lane >> 4;
  const int bh = blockIdx.x;
  const int qx = blockIdx.y;
  const int q0 = qx * 128;
  const size_t base = (size_t)bh * (1024*32);

  const int qrow = q0 + wid*32 + l31;
  const bf16x8 qf0 = *(const bf16x8*)(Q + base + (size_t)qrow*32 + l5*8);
  const bf16x8 qf1 = *(const bf16x8*)(Q + base + (size_t)qrow*32 + 16 + l5*8);

  f32x16 acc = {};     // O[q=(r&3)+8(r>>2)+4*l5][d=l31]
  float lsum = 0.f;

  // K staging: LDS chunk L = c*128 + kv  (c = chunk of 8 u16 within row).
  //   thread stages L=tid (c=tid>>7 in {0,1}) and L=tid+256 (c in {2,3}).
  const int kkv = tid & 127;
  const int kc0 = tid >> 7;            // 0 or 1
  const u16* Ksrc0 = Kb + base + (size_t)kkv*32 + kc0*8;
  const u16* Ksrc1 = Kb + base + (size_t)kkv*32 + (kc0+2)*8;
  // V staging: unchanged (slot = cp ^ (d&15), pre-swizzled source).
  const int vd = tid >> 4, vc = tid & 15;
  const u16* Vsrc0 = Vt + base + (size_t)(vd     )*1024 + (vc ^ (vd&15))*8;
  const u16* Vsrc1 = Vt + base + (size_t)(vd + 16)*1024 + (vc ^ (vd&15))*8;

  auto STAGE = [&](int buf, int kv0){
    u16* KsB = smem + buf*4096;          // chunk-column-major [4 c][128 kv]
    u16* VsB = smem + 8192 + buf*4096;   // [32 d][128 kv], chunk swz c^=(d&15)
    gll16(Ksrc0 + (size_t)kv0*32, KsB + tid*8);
    gll16(Ksrc1 + (size_t)kv0*32, KsB + (tid+256)*8);
    gll16(Vsrc0 + kv0, VsB + tid*8);
    gll16(Vsrc1 + kv0, VsB + (tid+256)*8);
  };

  STAGE(0, 0);
  __syncthreads();
  int cur = 0;
  for (int kv0 = 0; kv0 < 1024; kv0 += 128){
    if (kv0 + 128 < 1024) STAGE(cur^1, kv0 + 128);
    const u16* KsC = smem + cur*4096;
    const u16* VsC = smem + 8192 + cur*4096;

    #pragma unroll
    for (int G=0; G<4; ++G){
      // K-frag: row kv=32G+l31, chunk c=l5 (kf0) / 2+l5 (kf1); L = c*128 + kv
      bf16x8 kf0 = *(const bf16x8*)(KsC + ((     l5)*128 + 32*G + l31)*8);
      bf16x8 kf1 = *(const bf16x8*)(KsC + ((2 + l5)*128 + 32*G + l31)*8);
      f32x16 sf = __builtin_amdgcn_mfma_f32_32x32x16_bf16(kf0, qf0, (f32x16){}, 0, 0, 0);
      sf = __builtin_amdgcn_mfma_f32_32x32x16_bf16(kf1, qf1, sf, 0, 0, 0);

      u32 W[8];
      #pragma unroll
      for (int j=0;j<4;j++){
        float p0 = EXP2(sf[4*j+0]);
        float p1 = EXP2(sf[4*j+1]);
        float p2 = EXP2(sf[4*j+2]);
        float p3 = EXP2(sf[4*j+3]);
        lsum += (p0 + p1) + (p2 + p3);
        W[2*j+0] = cvtpk(p0, p1);
        W[2*j+1] = cvtpk(p2, p3);
      }

      #pragma unroll
      for (int sl=0; sl<2; ++sl){
        u32 a0 = W[4*sl + 0], b0 = W[4*sl + 2];
        u32 a1 = W[4*sl + 1], b1 = W[4*sl + 3];
        asm("v_permlane32_swap_b32 %0, %1" : "+v"(a0), "+v"(b0));
        asm("v_permlane32_swap_b32 %0, %1" : "+v"(a1), "+v"(b1));
        bf16x8 pa = __builtin_bit_cast(bf16x8, (u32x4v){a0, a1, b0, b1});
        const int cp = 4*G + 2*sl + l5;
        bf16x8 vb = *(const bf16x8*)(VsC + l31*128 + ((cp ^ (l31 & 15)) << 3));
        acc = __builtin_amdgcn_mfma_f32_32x32x16_bf16(pa, vb, acc, 0, 0, 0);
      }
    }
    __syncthreads();
    cur ^= 1;
  }

  // ---- epilogue part 1: normalize O, write T[16][256] (slot = chunk ^ row) --
  lsum += __shfl_xor(lsum, 32);
  float inv = 1.0f / lsum;
  u16* T = smem + 16384;
  #pragma unroll
  for (int r=0;r<16;r++){
    int qloc = (r&3) + 8*(r>>2) + 4*l5;
    float iv = __shfl(inv, qloc);
    int row = wid*4 + (r>>2);                 // 0..15
    int col = ((r&3) + 4*l5)*32 + l31;        // 0..255
    int ch  = col >> 3;
    T[row*256 + ((ch ^ row) << 3) + (col & 7)] = f2bf(acc[r] * iv);
  }

  // ---- epilogue part 2: mini-GEMM x1[16][256] = T @ Wo^T (Wo LDS dbuf) ------
  auto stageWo = [&](int buf, int k0){
    u16* dst = smem + buf*8192;
    #pragma unroll
    for (int j=0;j<4;j++){
      int ch = tid + j*256;
      int n = ch >> 2, c = ch & 3;
      int kcc = c ^ ((n>>1)&3);
      gll16(Wob + (size_t)n*256 + k0 + kcc*8, dst + ch*8);
    }
  };
  stageWo(0, 0);
  __syncthreads();   // covers T writes + WoS[0]

  f32x4 zf4 = {0.f,0.f,0.f,0.f};
  f32x4 acc2[4] = {zf4, zf4, zf4, zf4};
  int cw = 0;
  #pragma unroll
  for (int kk=0; kk<8; ++kk){
    if (kk < 7) stageWo(cw^1, (kk+1)*32);
    bf16x8 af = *(const bf16x8*)(T + lr*256 + (((4*kk + g) ^ lr) << 3));
    #pragma unroll
    for (int nt=0; nt<4; ++nt){
      int n = wid*64 + nt*16 + lr;
      bf16x8 bw = *(const bf16x8*)(smem + cw*8192 + n*32 + ((g ^ ((n>>1)&3)) << 3));
      acc2[nt] = __builtin_amdgcn_mfma_f32_16x16x32_bf16(af, bw, acc2[nt], 0, 0, 0);
    }
    __syncthreads();
    cw ^= 1;
  }

  // ---- epilogue part 3: bias + residual(xb) -> x1b + LN2 stats ---------------
  const int b = bh >> 3, h = bh & 7;
  const int srow0 = h*128 + qx*16;
  float ss = 0.f, qq = 0.f;
  #pragma unroll
  for (int nt=0; nt<4; ++nt){
    int col = wid*64 + nt*16 + lr;
    float bc = bo[col];
    #pragma unroll
    for (int rr=0; rr<4; ++rr){
      int row = g*4 + rr;
      size_t idx = ((size_t)b*1024 + srow0 + row)*256 + col;
      float v = bf2f(xb[idx]) + acc2[nt][rr] + bc;
      x1b[idx] = f2bf(v);
      ss += v; qq += v*v;
    }
  }
  #pragma unroll
  for (int o=32;o;o>>=1){ ss += __shfl_down(ss,o); qq += __shfl_down(qq,o); }
  float2* sred = (float2*)smem;   // staging region dead after final barrier
  if (lane == 0) sred[wid] = make_float2(ss, qq);
  __syncthreads();
  if (tid == 0){
    float S=0.f, QQ=0.f;
    #pragma unroll
    for (int k2=0;k2<4;k2++){ S += sred[k2].x; QQ += sred[k2].y; }
    part2[b*64 + h*8 + qx] = make_float2(S, QQ);
  }
}

// ---------------- launcher ---------------------------------------------------
extern "C" void kernel_launch(void* const* d_in, const int* in_sizes, int n_in,
                              void* d_out, int out_size, void* d_ws, size_t ws_size,
                              hipStream_t stream)
{
  const float* x      = (const float*)d_in[0];
  const float* gamma1 = (const float*)d_in[1];
  const float* beta1  = (const float*)d_in[2];
  const float* Wqkv   = (const float*)d_in[3];
  const float* bqkv   = (const float*)d_in[4];
  const float* Wo     = (const float*)d_in[5];
  const float* bo     = (const float*)d_in[6];
  const float* gamma2 = (const float*)d_in[7];
  const float* beta2  = (const float*)d_in[8];
  const float* W1     = (const float*)d_in[9];
  const float* b1     = (const float*)d_in[10];
  const float* W2     = (const float*)d_in[11];
  const float* b2     = (const float*)d_in[12];
  float* out = (float*)d_out;
  char* ws = (char*)d_ws;

  float2* part  = (float2*)(ws + 256);        //  8 KB  (LN1 partials, 16x64)
  float2* part2 = (float2*)(ws + 8448);       //  8 KB  (LN2 partials, 16x64)
  u16* wq   = (u16*)(ws + 16896);             // 384 KB (768x256)
  u16* wo   = (u16*)(ws + 410112);            // 128 KB (256x256)
  u16* w1   = (u16*)(ws + 541184);            // 512 KB (1024x256)
  u16* w2   = (u16*)(ws + 1065472);           // 512 KB (256x1024)
  u16* hbuf = (u16*)(ws + 1589760);           //  8 MB  LN output bf16
  u16* qb   = (u16*)(ws + 9978368);           //  8 MB  [B,H,S,32]
  u16* kb   = (u16*)(ws + 18366976);          //  8 MB  [B,H,S,32]
  u16* vtb  = (u16*)(ws + 26755584);          //  8 MB  [B,H,32,S]
  u16* xb   = (u16*)(ws + 35144192);          //  8 MB  x as bf16
  u16* midb = (u16*)(ws + 9978368);           // 32 MB  (reuses qb..xb region after attn)
  u16* x1b  = (u16*)(ws + 43532800);          //  8 MB  x1 residual, bf16

  // prep: weight cast + LN1 partials + x->bf16 (one launch, disjoint blocks)
  prep<<<1792, 256, 0, stream>>>(x, part, xb, Wqkv, Wo, W1, W2, wq, wo, w1, w2);

  // LN1 apply -> hbuf (bf16)
  ln_apply<<<dim3(64,16), 256, 0, stream>>>(xb, gamma1, beta1, part, hbuf);

  // QKV projection -> q (scaled), k, v^T
  gemm128<0><<<dim3(128,6), 256, 0, stream>>>(hbuf, wq, bqkv, qb, kb, vtb, 256, 768);

  // attention + O-proj + residual(xb) -> x1b (bf16) + LN2 partial stats
  attn32f<<<dim3(128,8), 256, 0, stream>>>(qb, kb, vtb, wo, bo, xb, x1b, part2);

  // LN2 apply (64 partials) -> hbuf (bf16)
  ln_apply<<<dim3(64,16), 256, 0, stream>>>(x1b, gamma2, beta2, part2, hbuf);

  // MLP1 + bias + ReLU -> midb (bf16)
  gemm128<2><<<dim3(128,8), 256, 0, stream>>>(hbuf, w1, b1, midb, nullptr, nullptr, 256, 1024);

  // MLP2 + bias + residual(x1b) -> out (fp32, final)
  gemm64<<<dim3(256,2), 256, 0, stream>>>(midb, w2, b2, x1b, out, 1024, 256);
}